// Round 7
// baseline (108.774 us; speedup 1.0000x reference)
//
#include <hip/hip_runtime.h>
#include <hip/hip_bf16.h>
#include <stdint.h>

typedef __bf16 bf16_8 __attribute__((ext_vector_type(8)));
typedef float f32x4 __attribute__((ext_vector_type(4)));
typedef unsigned int u32;
typedef unsigned short u16;

// Problem dims (fixed): B=8, R=4, N=1024, D_IN=D_OUT=256.
// Inputs FP32 (per reference); internal GEMMs bf16 MFMA; output FP32.

__device__ __forceinline__ u16 f2b(float f) {
    return __builtin_bit_cast(u16, __float2bfloat16(f));
}

// LDS tile: rows x 32 k (bf16) as 16B chunks, 4 chunks/row (64B row stride).
// Chunk (row,g) at index row*4 + (g ^ ((row>>1)&3)). Frag reads (fixed g, 16
// consecutive rows) measured conflict-free (R2-R5 profiles: 0 conflicts); the
// 64B row stride supplies a row-parity bank bit. (128B-row swz8 in R6 lost
// that bit -> 524K conflicts. Reverted.)
__device__ __forceinline__ u32 swz_off(u32 row, u32 g) {
    return (row * 4u + (g ^ ((row >> 1) & 3u))) * 16u;
}

__device__ __forceinline__ void gload_lds16(const void* g, void* l) {
    __builtin_amdgcn_global_load_lds((const __attribute__((address_space(1))) void*)g,
                                     (__attribute__((address_space(3))) void*)l, 16, 0, 0);
}

// Compiler-only memory scheduling fence: pins VMEM issue-order regions so
// counted s_waitcnt vmcnt(N) bookkeeping is deterministic.
__device__ __forceinline__ void memfence_sched() { asm volatile("" ::: "memory"); }

__device__ __forceinline__ uint4 pack8(float4 a, float4 b) {
    uint4 pk;
    pk.x = (u32)f2b(a.x) | ((u32)f2b(a.y) << 16);
    pk.y = (u32)f2b(a.z) | ((u32)f2b(a.w) << 16);
    pk.z = (u32)f2b(b.x) | ((u32)f2b(b.y) << 16);
    pk.w = (u32)f2b(b.z) | ((u32)f2b(b.w) << 16);
    return pk;
}

// C[128x128] += A[128xK]*B[Kx128]; used by y_gemm only (small, ~3us).
template <int KSTEPS>
__device__ __forceinline__ void gemm_core(const u16* pA, u32 strideA,
                                          const u16* pB, u32 strideB,
                                          char* smem, f32x4 acc[4][4]) {
    const u32 t    = threadIdx.x;
    const u32 lane = t & 63u;
    const u32 w    = t >> 6;
    const u32 wm   = (w >> 1) * 64u;
    const u32 wn   = (w & 1u) * 64u;
    const u32 waveByte = (t & 192u) * 16u;
    const u32 row0 = t >> 2;
    const u32 gg0  = (t & 3u) ^ ((row0 >> 1) & 3u);
    const u32 row1 = row0 + 64u;
    const u32 gg1  = ((t + 256u) & 3u) ^ ((row1 >> 1) & 3u);
    const u32 fr = lane & 15u;
    const u32 fg = lane >> 4;

    gload_lds16(pA + (size_t)row0 * strideA + gg0 * 8u, smem + waveByte);
    gload_lds16(pA + (size_t)row1 * strideA + gg1 * 8u, smem + waveByte + 4096u);
    gload_lds16(pB + (size_t)row0 * strideB + gg0 * 8u, smem + 16384u + waveByte);
    gload_lds16(pB + (size_t)row1 * strideB + gg1 * 8u, smem + 16384u + waveByte + 4096u);
    asm volatile("s_waitcnt vmcnt(0)" ::: "memory");
    __builtin_amdgcn_s_barrier();

    u32 c = 0;
#pragma unroll 2
    for (int ks = 0; ks < KSTEPS; ++ks) {
        char* curA = smem + c * 8192u;
        char* curB = smem + 16384u + c * 8192u;
        if (ks + 1 < KSTEPS) {
            char* nxtA = smem + (c ^ 1u) * 8192u;
            char* nxtB = smem + 16384u + (c ^ 1u) * 8192u;
            const u32 k0 = (u32)(ks + 1) * 32u;
            gload_lds16(pA + (size_t)row0 * strideA + k0 + gg0 * 8u, nxtA + waveByte);
            gload_lds16(pA + (size_t)row1 * strideA + k0 + gg1 * 8u, nxtA + waveByte + 4096u);
            gload_lds16(pB + (size_t)row0 * strideB + k0 + gg0 * 8u, nxtB + waveByte);
            gload_lds16(pB + (size_t)row1 * strideB + k0 + gg1 * 8u, nxtB + waveByte + 4096u);
        }

        bf16_8 af[4], bfv[4];
#pragma unroll
        for (int mt = 0; mt < 4; ++mt) {
            uint4 v = *(const uint4*)(curA + swz_off(wm + (u32)mt * 16u + fr, fg));
            af[mt] = __builtin_bit_cast(bf16_8, v);
        }
#pragma unroll
        for (int nt = 0; nt < 4; ++nt) {
            uint4 v = *(const uint4*)(curB + swz_off(wn + (u32)nt * 16u + fr, fg));
            bfv[nt] = __builtin_bit_cast(bf16_8, v);
        }
#pragma unroll
        for (int mt = 0; mt < 4; ++mt)
#pragma unroll
            for (int nt = 0; nt < 4; ++nt)
                acc[mt][nt] = __builtin_amdgcn_mfma_f32_16x16x32_bf16(af[mt], bfv[nt],
                                                                      acc[mt][nt], 0, 0, 0);

        if (ks + 1 < KSTEPS) {
            asm volatile("s_waitcnt vmcnt(0)" ::: "memory");
            __builtin_amdgcn_s_barrier();
        }
        c ^= 1u;
    }
}

// textb = bf16(text), layout preserved [B,N,D_in]. 8 elems/thread.
__global__ __launch_bounds__(256) void text_cvt_kernel(const float* t, u16* tb) {
    const u32 i8 = blockIdx.x * 256u + threadIdx.x;  // 262144 total
    const float4 a = ((const float4*)t)[i8 * 2u];
    const float4 b = ((const float4*)t)[i8 * 2u + 1u];
    ((uint4*)tb)[i8] = pack8(a, b);
}

// Wt[r][dout][din] = bf16(W[r][din][dout])
__global__ __launch_bounds__(256) void wt_cvt_kernel(const float* W, u16* Wt) {
    const u32 idx = blockIdx.x * 256u + threadIdx.x;  // 262144 total
    const u32 r = idx >> 16, rem = idx & 65535u, dout = rem >> 8, din = rem & 255u;
    Wt[idx] = f2b(W[(r << 16) + (din << 8) + dout]);
}

// Yt[b,r,dout,j] = bf16( sum_din Wt[r,dout,din] * textb[b,j,din] )
__global__ __launch_bounds__(256) void y_gemm_kernel(const u16* Wt, const u16* textb,
                                                     u16* Yt) {
    __shared__ char smem[32768];
    const u32 bx = blockIdx.x;                 // 512 blocks: b(3)|r(2)|m(1)|n(3)
    const u32 n0 = (bx & 7u) * 128u;
    const u32 m0 = ((bx >> 3) & 1u) * 128u;
    const u32 r  = (bx >> 4) & 3u;
    const u32 b  = bx >> 6;
    const u16* pA = Wt + (size_t)r * 65536u + (size_t)m0 * 256u;
    const u16* pB = textb + (size_t)b * 262144u + (size_t)n0 * 256u;
    f32x4 acc[4][4];
#pragma unroll
    for (int i = 0; i < 4; ++i)
#pragma unroll
        for (int j = 0; j < 4; ++j) acc[i][j] = (f32x4){0.f, 0.f, 0.f, 0.f};
    gemm_core<8>(pA, 256u, pB, 256u, smem, acc);

    const u32 lane = threadIdx.x & 63u, w = threadIdx.x >> 6;
    const u32 wm = (w >> 1) * 64u, wn = (w & 1u) * 64u;
    const u32 rit = (lane >> 4) * 4u, cit = lane & 15u;  // C: row=(lane>>4)*4+reg
    u16* yb = Yt + (size_t)(b * 4u + r) * 262144u;
#pragma unroll
    for (int mt = 0; mt < 4; ++mt)
#pragma unroll
        for (int nt = 0; nt < 4; ++nt) {
            const u32 m = m0 + wm + (u32)mt * 16u + rit;
            const u32 n = n0 + wn + (u32)nt * 16u + cit;
#pragma unroll
            for (int rg = 0; rg < 4; ++rg)
                yb[(size_t)(m + (u32)rg) * 1024u + n] = f2b(acc[mt][nt][rg]);
        }
}

// FULLY FUSED: out[b,i,d] = bias[d] + sum_r inv[b,r,i] * sum_j adj[b,r,i,j]*Yt[b,r,d,j]
//
// Block = 32 i-rows x full d=256; loops r=0..3 with K=1024 each. Grid 256 =
// 8b x 32 i-tiles -> adj read EXACTLY once; no partial array, no reduce
// kernel (saves 64 MB traffic + a dispatch). Per-relation accumulator accR
// is rescaled by inv_r (known only after r's full rowsum) into accT at each
// r-boundary; accT + bias written straight to out.
// Pipeline = the verified R5 depth-2 counted-vmcnt skeleton per relation:
// 3 VMEM/iter (1x A float2 + 2x B gload_lds, tile ks+2), vmcnt(3) end-of-
// iter, 3 B-buffers / 2 A-buffers / 2 A-reg sets, 2-iter peel. 32-k-row LDS
// layout (zero measured conflicts). All staging linear-dst; sources
// pre-swizzled (involution both sides).
// XCD remap: batch b -> XCD b; Yt[b] (2 MB) L2-resident per XCD.
// 512 thr = 8 waves (2M x 4N), wave tile 16 i x 64 d, accR/accT 4x f32x4.
__global__ __launch_bounds__(512, 2) void adj_gemm_out(const float* adj, const u16* Yt,
                                                       const float* bias, float* out) {
    __shared__ char smem[53376];
    char* bufA = smem;                     // 2 x 2048  (32 rows x 32k bf16)
    char* bufB = smem + 4096;              // 3 x 16384 (256 rows x 32k bf16)
    float* sInv = (float*)(smem + 53248);  // 32 row inverses

    const u32 raw = blockIdx.x;            // 256 = 8 XCDs x 32
    const u32 bx = (raw & 7u) * 32u + (raw >> 3);
    const u32 i0 = (bx & 31u) * 32u;
    const u32 b  = bx >> 5;

    const u32 t = threadIdx.x, lane = t & 63u, w = t >> 6;
    const u32 wi = (w >> 2) * 16u;         // 2 M-groups
    const u32 wd = (w & 3u) * 64u;         // 4 N-groups
    const u32 fr = lane & 15u, fg = lane >> 4;

    // A staging: thread t owns row sRow=t>>4, one float2 (2 f32) per k-tile,
    // ds_write_b32 at linear byte t*4. Linear slot -> physical chunk
    // cLin=(t>>2)&3; it must hold logical chunk cLin^sw, so the GLOBAL source
    // k-offset is pre-swizzled: aKoff = (cLin^sw)*8 + (t&3)*2.
    const u32 sRow = t >> 4;                               // 0..31
    const u32 aKoff = (((t >> 2) & 3u) ^ ((sRow >> 1) & 3u)) * 8u + (t & 3u) * 2u;

    // B staging (verified R5 map): chunks t and t+512 of the 256x32k tile,
    // linear LDS dst (wave base + lane*16), global source pre-swizzled.
    const u32 brow0 = t >> 2;                              // 0..127
    const u32 brow1 = (t + 512u) >> 2;                     // 128..255
    const u32 bg0 = (t & 3u) ^ ((brow0 >> 1) & 3u);
    const u32 bg1 = (t & 3u) ^ ((brow1 >> 1) & 3u);
    const u32 waveB = (t & 448u) * 16u;

    f32x4 accT[4], accR[4];
#pragma unroll
    for (int i = 0; i < 4; ++i) accT[i] = (f32x4){0.f, 0.f, 0.f, 0.f};

#pragma unroll 1
    for (u32 r = 0; r < 4u; ++r) {
        const float* pAr = adj + (((size_t)(b * 4u + r)) << 20) + (size_t)i0 * 1024u;
        const u16*   pBr = Yt + (((size_t)(b * 4u + r)) << 18);
        const float* aSrc = pAr + (size_t)sRow * 1024u + aKoff;
        const u16* b0p = pBr + (size_t)brow0 * 1024u + bg0 * 8u;
        const u16* b1p = pBr + (size_t)brow1 * 1024u + bg1 * 8u;

#pragma unroll
        for (int i = 0; i < 4; ++i) accR[i] = (f32x4){0.f, 0.f, 0.f, 0.f};
        float s0 = 0.f;
        float2 rA[2];

        auto stageB = [&](u32 kt, char* dst) {
            gload_lds16(b0p + kt * 32u, dst + waveB);
            gload_lds16(b1p + kt * 32u, dst + 8192u + waveB);
        };
        auto packA = [&](float2 a, char* dst) {
            s0 += a.x + a.y;
            *(u32*)(dst + t * 4u) = (u32)f2b(a.x) | ((u32)f2b(a.y) << 16);
        };
        auto do_mfma = [&](char* curA, char* curB) {
            uint4 va = *(const uint4*)(curA + swz_off(wi + fr, fg));
            bf16_8 af = __builtin_bit_cast(bf16_8, va);
#pragma unroll
            for (int nt = 0; nt < 4; ++nt) {
                uint4 v = *(const uint4*)(curB + swz_off(wd + (u32)nt * 16u + fr, fg));
                bf16_8 bfv = __builtin_bit_cast(bf16_8, v);
                accR[nt] = __builtin_amdgcn_mfma_f32_16x16x32_bf16(af, bfv, accR[nt],
                                                                   0, 0, 0);
            }
        };

        // ---- Prologue: issue {A0,B0x2} then {A1,B1x2}; pack A0; keep 3 in flight.
        rA[0] = *(const float2*)(aSrc);
        stageB(0u, bufB);
        memfence_sched();
        rA[1] = *(const float2*)(aSrc + 32u);
        stageB(1u, bufB + 16384u);
        memfence_sched();
        packA(rA[0], bufA);    // implicit wait drains A(0) only
        asm volatile("s_waitcnt vmcnt(3) lgkmcnt(0)" ::: "memory");  // B(0) landed
        __builtin_amdgcn_s_barrier();

        // ---- Main: ks=0..29, compute tile ks, issue tile ks+2 (3 VMEM ops).
#pragma unroll 6
        for (int ks = 0; ks < 30; ++ks) {
            const u32 cA = (u32)ks & 1u, nA = cA ^ 1u;
            packA(rA[nA], bufA + nA * 2048u);           // A(ks+1) -> LDS
            rA[cA] = *(const float2*)(aSrc + (u32)(ks + 2) * 32u);      // 1 op
            stageB((u32)(ks + 2), bufB + (u32)((ks + 2) % 3) * 16384u); // 2 ops
            do_mfma(bufA + cA * 2048u, bufB + (u32)(ks % 3) * 16384u);
            asm volatile("s_waitcnt vmcnt(3) lgkmcnt(0)" ::: "memory");
            __builtin_amdgcn_s_barrier();
        }
        // ---- Peel ks=30: pack A(31), no new issues.
        packA(rA[1], bufA + 2048u);
        do_mfma(bufA, bufB);                            // tile 30: bufB[0]
        asm volatile("s_waitcnt vmcnt(0) lgkmcnt(0)" ::: "memory");
        __builtin_amdgcn_s_barrier();
        // ---- Peel ks=31.
        do_mfma(bufA + 2048u, bufB + 16384u);           // tile 31: bufB[1]

        // ---- Relation epilogue: rowsum (16 threads per row, lane-contig).
        s0 += __shfl_down(s0, 8, 16);
        s0 += __shfl_down(s0, 4, 16);
        s0 += __shfl_down(s0, 2, 16);
        s0 += __shfl_down(s0, 1, 16);
        if ((t & 15u) == 0u) sInv[sRow] = (s0 == 0.f) ? 0.f : 1.f / s0;
        __syncthreads();   // sInv visible; also fences LDS reads of this r
                           // against next r's staging writes.
#pragma unroll
        for (int rg = 0; rg < 4; ++rg) {
            const float inv = sInv[wi + fg * 4u + (u32)rg];
#pragma unroll
            for (int nt = 0; nt < 4; ++nt) accT[nt][rg] += accR[nt][rg] * inv;
        }
    }

    // ---- Output: out[b, i0+row, col] = accT + bias[col]
    float* ob = out + ((size_t)b << 18) + (size_t)i0 * 256u;
#pragma unroll
    for (int nt = 0; nt < 4; ++nt) {
        const u32 col = wd + (u32)nt * 16u + fr;
        const float bv = bias[col];
#pragma unroll
        for (int rg = 0; rg < 4; ++rg) {
            const u32 mRow = wi + fg * 4u + (u32)rg;
            ob[(size_t)mRow * 256u + col] = accT[nt][rg] + bv;
        }
    }
}

extern "C" void kernel_launch(void* const* d_in, const int* in_sizes, int n_in,
                              void* d_out, int out_size, void* d_ws, size_t ws_size,
                              hipStream_t stream) {
    const float* text = (const float*)d_in[0];  // [8,1024,256] fp32
    const float* adj  = (const float*)d_in[1];  // [8,4,1024,1024] fp32
    const float* wgt  = (const float*)d_in[2];  // [4,256,256] fp32
    const float* bias = (const float*)d_in[3];  // [256] fp32
    float* out = (float*)d_out;                 // [8,1024,256] fp32

    char* ws = (char*)d_ws;
    u16* Yt    = (u16*)ws;                      // 16 MB  bf16 [B,R,256,1024]
    u16* textb = (u16*)(ws + 16777216u);        //  4 MB  bf16 [B,N,256]
    u16* Wt    = (u16*)(ws + 20971520u);        // 512 KB bf16 [R,256,256]

    text_cvt_kernel<<<1024, 256, 0, stream>>>(text, textb);
    wt_cvt_kernel<<<1024, 256, 0, stream>>>(wgt, Wt);
    y_gemm_kernel<<<512, 256, 0, stream>>>(Wt, textb, Yt);
    adj_gemm_out<<<256, 512, 0, stream>>>(adj, Yt, bias, out);
}

// Round 8
// 66.056 us; speedup vs baseline: 1.6467x; 1.6467x over previous
//
#include <hip/hip_runtime.h>
#include <hip/hip_bf16.h>
#include <stdint.h>

typedef __bf16 bf16_8 __attribute__((ext_vector_type(8)));
typedef float f32x4 __attribute__((ext_vector_type(4)));
typedef unsigned int u32;
typedef unsigned short u16;

// Problem dims (fixed): B=8, R=4, N=1024, D_IN=D_OUT=256.
// Inputs FP32 (per reference); internal GEMMs bf16 MFMA; output FP32.

__device__ __forceinline__ u16 f2b(float f) {
    return __builtin_bit_cast(u16, __float2bfloat16(f));
}

// LDS tile: rows x 32 k (bf16) as 16B chunks, 4 chunks/row (64B row stride).
// Chunk (row,g) at index row*4 + (g ^ ((row>>1)&3)). Frag reads (fixed g, 16
// consecutive rows) measured conflict-free (R2-R5 profiles: 0 conflicts).
__device__ __forceinline__ u32 swz_off(u32 row, u32 g) {
    return (row * 4u + (g ^ ((row >> 1) & 3u))) * 16u;
}

__device__ __forceinline__ void gload_lds16(const void* g, void* l) {
    __builtin_amdgcn_global_load_lds((const __attribute__((address_space(1))) void*)g,
                                     (__attribute__((address_space(3))) void*)l, 16, 0, 0);
}

// Compiler-only memory scheduling fence: pins VMEM issue-order regions so
// counted s_waitcnt vmcnt(N) bookkeeping is deterministic.
__device__ __forceinline__ void memfence_sched() { asm volatile("" ::: "memory"); }

__device__ __forceinline__ uint4 pack8(float4 a, float4 b) {
    uint4 pk;
    pk.x = (u32)f2b(a.x) | ((u32)f2b(a.y) << 16);
    pk.y = (u32)f2b(a.z) | ((u32)f2b(a.w) << 16);
    pk.z = (u32)f2b(b.x) | ((u32)f2b(b.y) << 16);
    pk.w = (u32)f2b(b.z) | ((u32)f2b(b.w) << 16);
    return pk;
}

// C[128x128] += A[128xK]*B[Kx128]; used by y_gemm only (small, ~3us).
template <int KSTEPS>
__device__ __forceinline__ void gemm_core(const u16* pA, u32 strideA,
                                          const u16* pB, u32 strideB,
                                          char* smem, f32x4 acc[4][4]) {
    const u32 t    = threadIdx.x;
    const u32 lane = t & 63u;
    const u32 w    = t >> 6;
    const u32 wm   = (w >> 1) * 64u;
    const u32 wn   = (w & 1u) * 64u;
    const u32 waveByte = (t & 192u) * 16u;
    const u32 row0 = t >> 2;
    const u32 gg0  = (t & 3u) ^ ((row0 >> 1) & 3u);
    const u32 row1 = row0 + 64u;
    const u32 gg1  = ((t + 256u) & 3u) ^ ((row1 >> 1) & 3u);
    const u32 fr = lane & 15u;
    const u32 fg = lane >> 4;

    gload_lds16(pA + (size_t)row0 * strideA + gg0 * 8u, smem + waveByte);
    gload_lds16(pA + (size_t)row1 * strideA + gg1 * 8u, smem + waveByte + 4096u);
    gload_lds16(pB + (size_t)row0 * strideB + gg0 * 8u, smem + 16384u + waveByte);
    gload_lds16(pB + (size_t)row1 * strideB + gg1 * 8u, smem + 16384u + waveByte + 4096u);
    asm volatile("s_waitcnt vmcnt(0)" ::: "memory");
    __builtin_amdgcn_s_barrier();

    u32 c = 0;
#pragma unroll 2
    for (int ks = 0; ks < KSTEPS; ++ks) {
        char* curA = smem + c * 8192u;
        char* curB = smem + 16384u + c * 8192u;
        if (ks + 1 < KSTEPS) {
            char* nxtA = smem + (c ^ 1u) * 8192u;
            char* nxtB = smem + 16384u + (c ^ 1u) * 8192u;
            const u32 k0 = (u32)(ks + 1) * 32u;
            gload_lds16(pA + (size_t)row0 * strideA + k0 + gg0 * 8u, nxtA + waveByte);
            gload_lds16(pA + (size_t)row1 * strideA + k0 + gg1 * 8u, nxtA + waveByte + 4096u);
            gload_lds16(pB + (size_t)row0 * strideB + k0 + gg0 * 8u, nxtB + waveByte);
            gload_lds16(pB + (size_t)row1 * strideB + k0 + gg1 * 8u, nxtB + waveByte + 4096u);
        }

        bf16_8 af[4], bfv[4];
#pragma unroll
        for (int mt = 0; mt < 4; ++mt) {
            uint4 v = *(const uint4*)(curA + swz_off(wm + (u32)mt * 16u + fr, fg));
            af[mt] = __builtin_bit_cast(bf16_8, v);
        }
#pragma unroll
        for (int nt = 0; nt < 4; ++nt) {
            uint4 v = *(const uint4*)(curB + swz_off(wn + (u32)nt * 16u + fr, fg));
            bfv[nt] = __builtin_bit_cast(bf16_8, v);
        }
#pragma unroll
        for (int mt = 0; mt < 4; ++mt)
#pragma unroll
            for (int nt = 0; nt < 4; ++nt)
                acc[mt][nt] = __builtin_amdgcn_mfma_f32_16x16x32_bf16(af[mt], bfv[nt],
                                                                      acc[mt][nt], 0, 0, 0);

        if (ks + 1 < KSTEPS) {
            asm volatile("s_waitcnt vmcnt(0)" ::: "memory");
            __builtin_amdgcn_s_barrier();
        }
        c ^= 1u;
    }
}

// textb = bf16(text), layout preserved [B,N,D_in]. 8 elems/thread.
__global__ __launch_bounds__(256) void text_cvt_kernel(const float* t, u16* tb) {
    const u32 i8 = blockIdx.x * 256u + threadIdx.x;  // 262144 total
    const float4 a = ((const float4*)t)[i8 * 2u];
    const float4 b = ((const float4*)t)[i8 * 2u + 1u];
    ((uint4*)tb)[i8] = pack8(a, b);
}

// Wt[r][dout][din] = bf16(W[r][din][dout])
__global__ __launch_bounds__(256) void wt_cvt_kernel(const float* W, u16* Wt) {
    const u32 idx = blockIdx.x * 256u + threadIdx.x;  // 262144 total
    const u32 r = idx >> 16, rem = idx & 65535u, dout = rem >> 8, din = rem & 255u;
    Wt[idx] = f2b(W[(r << 16) + (din << 8) + dout]);
}

// Yt[b,r,dout,j] = bf16( sum_din Wt[r,dout,din] * textb[b,j,din] )
__global__ __launch_bounds__(256) void y_gemm_kernel(const u16* Wt, const u16* textb,
                                                     u16* Yt) {
    __shared__ char smem[32768];
    const u32 bx = blockIdx.x;                 // 512 blocks: b(3)|r(2)|m(1)|n(3)
    const u32 n0 = (bx & 7u) * 128u;
    const u32 m0 = ((bx >> 3) & 1u) * 128u;
    const u32 r  = (bx >> 4) & 3u;
    const u32 b  = bx >> 6;
    const u16* pA = Wt + (size_t)r * 65536u + (size_t)m0 * 256u;
    const u16* pB = textb + (size_t)b * 262144u + (size_t)n0 * 256u;
    f32x4 acc[4][4];
#pragma unroll
    for (int i = 0; i < 4; ++i)
#pragma unroll
        for (int j = 0; j < 4; ++j) acc[i][j] = (f32x4){0.f, 0.f, 0.f, 0.f};
    gemm_core<8>(pA, 256u, pB, 256u, smem, acc);

    const u32 lane = threadIdx.x & 63u, w = threadIdx.x >> 6;
    const u32 wm = (w >> 1) * 64u, wn = (w & 1u) * 64u;
    const u32 rit = (lane >> 4) * 4u, cit = lane & 15u;  // C: row=(lane>>4)*4+reg
    u16* yb = Yt + (size_t)(b * 4u + r) * 262144u;
#pragma unroll
    for (int mt = 0; mt < 4; ++mt)
#pragma unroll
        for (int nt = 0; nt < 4; ++nt) {
            const u32 m = m0 + wm + (u32)mt * 16u + rit;
            const u32 n = n0 + wn + (u32)nt * 16u + cit;
#pragma unroll
            for (int rg = 0; rg < 4; ++rg)
                yb[(size_t)(m + (u32)rg) * 1024u + n] = f2b(acc[mt][nt][rg]);
        }
}

// partial[b,r,i,d] = inv[b,r,i] * sum_j adj[b,r,i,j]*Yt[b,r,d,j]
//
// BM=128 x full d=256, BK=32, K=1024. Grid 256 = 8b x 4r x 8 i-tiles:
// adj read exactly once; HALF the K-step slots of R5 (256 blk x 32 steps
// / 256 CU = 32 slots/CU vs 64) — per the R3/R5/R7 slot model (time ~
// slots x 0.8us fixed step overhead), this is the direct lever.
// 512 thr = 8 waves (2M x 4N), wave tile 64i x 64d, acc[4][4].
// Depth-2 counted-vmcnt pipeline (verbatim R5 skeleton): 4 VMEM/iter
// (2x A float4 + 2x B gload_lds, tile ks+2), vmcnt(4) end-of-iter.
// Invariant entering iter ks: bufA[ks&1]=A(ks), bufB[ks%3]=B(ks),
// rA[(ks+1)&1]=A(ks+1) regs; outstanding = {A(ks+1)x2, B(ks+1)x2}.
// A-staging (R2's proven map at 512 thr): thread t owns row t>>2, one 16B
// chunk (8 f32 -> 8 bf16): 2 float4 loads, 1 uint4 ds_write at linear byte
// t*16; global source chunk pre-swizzled (involution with frag read).
// B-staging / swizzle / rowsum-in-pack: verbatim R5.
__global__ __launch_bounds__(512, 2) void adj_gemm_partial(const float* adj,
                                                           const u16* Yt,
                                                           float* partial) {
    __shared__ char smem[66048];
    char* bufA = smem;                     // 2 x 8192  (128 rows x 32k bf16)
    char* bufB = smem + 16384;             // 3 x 16384 (256 rows x 32k bf16)
    float* sInv = (float*)(smem + 65536);  // 128 row inverses

    // XCD-contiguous bijective remap (256 = 8 XCDs x 32): XCD x gets batch
    // b = x entirely -> Yt[b] (2 MB) stays in that XCD's 4 MB L2.
    const u32 raw = blockIdx.x;
    const u32 bx = (raw & 7u) * 32u + (raw >> 3);
    const u32 i0 = (bx & 7u) * 128u;
    const u32 r  = (bx >> 3) & 3u;
    const u32 b  = bx >> 5;

    const float* pA = adj + (((size_t)(b * 4u + r)) << 20) + (size_t)i0 * 1024u;
    const u16*   pB = Yt + (((size_t)(b * 4u + r)) << 18);

    const u32 t = threadIdx.x, lane = t & 63u, w = t >> 6;
    const u32 wm = (w >> 2) * 64u;         // 2 M-groups (0/64)
    const u32 wn = (w & 3u) * 64u;         // 4 N-groups (0..192)
    const u32 fr = lane & 15u, fg = lane >> 4;

    // A staging map: row sRow = t>>2 (0..127), linear chunk cLin = t&3; the
    // global source chunk is cLin ^ rowparity so the linear ds_write at t*16
    // lands where the swizzled frag read expects it.
    const u32 sRow = t >> 2;
    const u32 cSwz = (t & 3u) ^ ((sRow >> 1) & 3u);
    const float* aSrc = pA + (size_t)sRow * 1024u + cSwz * 8u;

    // B staging map (verbatim R5): chunks t and t+512 of the 256-row tile,
    // linear LDS dst (wave base + lane*16), global source pre-swizzled.
    const u32 brow0 = t >> 2;                              // 0..127
    const u32 brow1 = (t + 512u) >> 2;                     // 128..255
    const u32 bg0 = (t & 3u) ^ ((brow0 >> 1) & 3u);
    const u32 bg1 = (t & 3u) ^ ((brow1 >> 1) & 3u);
    const u16* b0p = pB + (size_t)brow0 * 1024u + bg0 * 8u;
    const u16* b1p = pB + (size_t)brow1 * 1024u + bg1 * 8u;
    const u32 waveB = (t & 448u) * 16u;    // wave-uniform LDS byte base

    f32x4 acc[4][4];
#pragma unroll
    for (int i = 0; i < 4; ++i)
#pragma unroll
        for (int j = 0; j < 4; ++j) acc[i][j] = (f32x4){0.f, 0.f, 0.f, 0.f};

    float s0 = 0.f;
    float4 rA[2][2];

    auto loadA = [&](float4* dst, u32 kt) {
        dst[0] = *(const float4*)(aSrc + kt * 32u);
        dst[1] = *(const float4*)(aSrc + kt * 32u + 4u);
    };
    auto stageB = [&](u32 kt, char* dst) {
        gload_lds16(b0p + kt * 32u, dst + waveB);
        gload_lds16(b1p + kt * 32u, dst + 8192u + waveB);
    };
    auto packA = [&](const float4* a2, char* dst) {
        s0 += (a2[0].x + a2[0].y + a2[0].z + a2[0].w)
            + (a2[1].x + a2[1].y + a2[1].z + a2[1].w);
        *(uint4*)(dst + t * 16u) = pack8(a2[0], a2[1]);
    };
    auto do_mfma = [&](char* curA, char* curB) {
        bf16_8 af[4], bfv[4];
#pragma unroll
        for (int mt = 0; mt < 4; ++mt) {
            uint4 v = *(const uint4*)(curA + swz_off(wm + (u32)mt * 16u + fr, fg));
            af[mt] = __builtin_bit_cast(bf16_8, v);
        }
#pragma unroll
        for (int nt = 0; nt < 4; ++nt) {
            uint4 v = *(const uint4*)(curB + swz_off(wn + (u32)nt * 16u + fr, fg));
            bfv[nt] = __builtin_bit_cast(bf16_8, v);
        }
#pragma unroll
        for (int mt = 0; mt < 4; ++mt)
#pragma unroll
            for (int nt = 0; nt < 4; ++nt)
                acc[mt][nt] = __builtin_amdgcn_mfma_f32_16x16x32_bf16(af[mt], bfv[nt],
                                                                      acc[mt][nt], 0, 0, 0);
    };

    // ---- Prologue: issue {A0x2,B0x2} then {A1x2,B1x2}; pack A0; keep 4 in flight.
    loadA(rA[0], 0u);
    stageB(0u, bufB);
    memfence_sched();
    loadA(rA[1], 1u);
    stageB(1u, bufB + 16384u);
    memfence_sched();
    packA(rA[0], bufA);    // implicit wait drains A(0)x2 only
    asm volatile("s_waitcnt vmcnt(4) lgkmcnt(0)" ::: "memory");  // B(0) landed
    __builtin_amdgcn_s_barrier();

    // ---- Main: ks=0..29, compute tile ks, issue tile ks+2 (4 VMEM ops).
#pragma unroll 6
    for (int ks = 0; ks < 30; ++ks) {
        const u32 cA = (u32)ks & 1u, nA = cA ^ 1u;
        packA(rA[nA], bufA + nA * 8192u);              // A(ks+1) -> LDS
        loadA(rA[cA], (u32)(ks + 2));                  // 2 ops
        stageB((u32)(ks + 2), bufB + (u32)((ks + 2) % 3) * 16384u);  // 2 ops
        do_mfma(bufA + cA * 8192u, bufB + (u32)(ks % 3) * 16384u);
        asm volatile("s_waitcnt vmcnt(4) lgkmcnt(0)" ::: "memory");
        __builtin_amdgcn_s_barrier();
    }
    // ---- Peel ks=30: pack A(31), no new issues.
    packA(rA[1], bufA + 8192u);
    do_mfma(bufA, bufB);                               // tile 30: bufB[30%3=0]
    asm volatile("s_waitcnt vmcnt(0) lgkmcnt(0)" ::: "memory");
    __builtin_amdgcn_s_barrier();
    // ---- Peel ks=31.
    do_mfma(bufA + 8192u, bufB + 16384u);              // tile 31: bufB[1]

    // rowsum: 4 consecutive threads (t&3) hold k-slices of row sRow
    s0 += __shfl_down(s0, 2, 64);
    s0 += __shfl_down(s0, 1, 64);
    if ((t & 3u) == 0u) sInv[sRow] = (s0 == 0.f) ? 0.f : 1.f / s0;
    __syncthreads();

    float* pp = partial + (((size_t)(b * 4u + r)) << 18) + (size_t)i0 * 256u;
#pragma unroll
    for (int mt = 0; mt < 4; ++mt)
#pragma unroll
        for (int rg = 0; rg < 4; ++rg) {
            const u32 mRow = wm + (u32)mt * 16u + fg * 4u + (u32)rg;
            const float inv = sInv[mRow];
#pragma unroll
            for (int nt = 0; nt < 4; ++nt)
                pp[(size_t)mRow * 256u + wn + (u32)nt * 16u + fr] = acc[mt][nt][rg] * inv;
        }
}

// out[b,i,d] = bias[d] + sum_r partial[b,r,i,d]
__global__ __launch_bounds__(256) void reduce_kernel(const float* partial,
                                                     const float* bias, float* out) {
    const u32 i4 = blockIdx.x * 256u + threadIdx.x;  // 524288 threads, 4 f32 each
    const u32 base = i4 * 4u;
    const u32 b = base >> 18;
    const u32 rem = base & 262143u;
    float4 s = ((const float4*)bias)[i4 & 63u];
#pragma unroll
    for (u32 r = 0; r < 4; ++r) {
        const float4 v = *(const float4*)(partial + (((size_t)(b * 4u + r)) << 18) + rem);
        s.x += v.x; s.y += v.y; s.z += v.z; s.w += v.w;
    }
    ((float4*)out)[i4] = s;
}

extern "C" void kernel_launch(void* const* d_in, const int* in_sizes, int n_in,
                              void* d_out, int out_size, void* d_ws, size_t ws_size,
                              hipStream_t stream) {
    const float* text = (const float*)d_in[0];  // [8,1024,256] fp32
    const float* adj  = (const float*)d_in[1];  // [8,4,1024,1024] fp32
    const float* wgt  = (const float*)d_in[2];  // [4,256,256] fp32
    const float* bias = (const float*)d_in[3];  // [256] fp32
    float* out = (float*)d_out;                 // [8,1024,256] fp32

    char* ws = (char*)d_ws;
    u16* Yt        = (u16*)ws;                      // 16 MB  bf16 [B,R,256,1024]
    u16* textb     = (u16*)(ws + 16777216u);        //  4 MB  bf16 [B,N,256]
    u16* Wt        = (u16*)(ws + 20971520u);        // 512 KB bf16 [R,256,256]
    float* partial = (float*)(ws + 21495808u);      // 32 MB  fp32 [B,R,N,256]

    text_cvt_kernel<<<1024, 256, 0, stream>>>(text, textb);
    wt_cvt_kernel<<<1024, 256, 0, stream>>>(wgt, Wt);
    y_gemm_kernel<<<512, 256, 0, stream>>>(Wt, textb, Yt);
    adj_gemm_partial<<<256, 512, 0, stream>>>(adj, Yt, partial);
    reduce_kernel<<<2048, 256, 0, stream>>>(partial, bias, out);
}